// Round 4
// baseline (128.342 us; speedup 1.0000x reference)
//
#include <hip/hip_runtime.h>

#define Hd 128
#define Wd 128
#define Cd 64
#define COd 64
#define Bd 4
#define HWd (Hd*Wd)
#define KS 18   // 576 / 32 K-steps

typedef __attribute__((ext_vector_type(8))) short  short8;
typedef __attribute__((ext_vector_type(4))) float  f32x4;

// Static device scratch.
__device__ __align__(16) short g_wbf[COd*576];                   // bf16 W[co][k], k=t*64+c
__device__ __align__(16) float g_wtoff[9*Cd*4];                  // w_off^T [t][c][o]
__device__ __align__(16) unsigned short g_xt[(size_t)Bd*HWd*Cd]; // bf16 NHWC x

static __device__ __forceinline__ unsigned short f2bf(float v) {
    unsigned u = __float_as_uint(v);
    u += 0x7FFFu + ((u >> 16) & 1u);   // RNE
    return (unsigned short)(u >> 16);
}
static __device__ __forceinline__ float bflo(unsigned u) { return __uint_as_float(u << 16); }
static __device__ __forceinline__ float bfhi(unsigned u) { return __uint_as_float(u & 0xFFFF0000u); }

// One prep kernel: [0,512) NHWC repack ; [512,656) W->bf16 ; [656,665) w_off transpose.
__global__ __launch_bounds__(256) void k_prep(const float* __restrict__ x,
                                              const float* __restrict__ weight,
                                              const float* __restrict__ w_off) {
    int bid = blockIdx.x;
    if (bid < 512) {
        int b = bid >> 7, y = bid & 127;
        int px = threadIdx.x & 127;
        int h  = threadIdx.x >> 7;
        const float* xb = x + (size_t)b*Cd*HWd + y*Wd + px;
        unsigned short* ob = g_xt + ((size_t)(b*HWd) + y*Wd + px)*Cd + h*32;
        #pragma unroll
        for (int oct = 0; oct < 4; ++oct) {
            unsigned pk[4];
            #pragma unroll
            for (int e = 0; e < 4; ++e) {
                float v0 = xb[(size_t)(h*32 + oct*8 + 2*e    )*HWd];
                float v1 = xb[(size_t)(h*32 + oct*8 + 2*e + 1)*HWd];
                pk[e] = (unsigned)f2bf(v0) | ((unsigned)f2bf(v1) << 16);
            }
            *(uint4*)(ob + oct*8) = make_uint4(pk[0], pk[1], pk[2], pk[3]);
        }
    } else if (bid < 656) {
        int g = (bid - 512)*256 + threadIdx.x;     // 64*576
        if (g < COd*576) {
            int co = g / 576, k = g % 576;
            int t = k >> 6, c = k & 63;            // k = t*64 + c
            g_wbf[g] = (short)f2bf(weight[(co*Cd + c)*9 + t]);
        }
    } else {
        int g = (bid - 656)*256 + threadIdx.x;     // 9*64*4 = 2304
        if (g < 9*Cd*4) {
            int t = g >> 8, c = (g >> 2) & 63, o = g & 3;
            g_wtoff[g] = w_off[(o*Cd + c)*9 + t];
        }
    }
}

__global__ __launch_bounds__(512, 8) void k_deform(const float* __restrict__ b_off,
                                                   const float* __restrict__ bias,
                                                   float* __restrict__ out) {
    __shared__ uint4  lds_b[KS*2*64];    // 36864 B (aliased for offset partials)
    __shared__ float4 lds_po[32];        // final per-px offsets
    float4* lds_part = (float4*)lds_b;   // [32][16]

    int gid = blockIdx.x;                // 2048 = b*512 + i*4 + jt
    int b  = gid >> 9;
    int r  = gid & 511;
    int i  = r >> 2;
    int j0 = (r & 3) << 5;
    int tid = threadIdx.x;

    const unsigned short* xb = g_xt + (size_t)b*HWd*Cd;

    // ---- Fused offsets conv: thread = px(32) x sub(16); sub = tap-half x oct ----
    {
        int px  = tid >> 4, sub = tid & 15;
        int oct = sub & 7,  th  = sub >> 3;
        int j = j0 + px;
        float4 a = make_float4(0.f, 0.f, 0.f, 0.f);
        for (int t = th ? 5 : 0; t < (th ? 9 : 5); ++t) {
            int yy = i + (t/3 - 1), xx = j + (t%3 - 1);
            if (yy < 0 || yy > 127 || xx < 0 || xx > 127) continue;
            uint4 u = *(const uint4*)(xb + (size_t)(yy*Wd + xx)*Cd + oct*8);
            unsigned aa[4] = {u.x, u.y, u.z, u.w};
            #pragma unroll
            for (int e = 0; e < 4; ++e) {
                int c = oct*8 + 2*e;
                float v0 = bflo(aa[e]), v1 = bfhi(aa[e]);
                float4 w0 = *(const float4*)(g_wtoff + (t*Cd + c    )*4);
                float4 w1 = *(const float4*)(g_wtoff + (t*Cd + c + 1)*4);
                a.x = fmaf(v0, w0.x, fmaf(v1, w1.x, a.x));
                a.y = fmaf(v0, w0.y, fmaf(v1, w1.y, a.y));
                a.z = fmaf(v0, w0.z, fmaf(v1, w1.z, a.z));
                a.w = fmaf(v0, w0.w, fmaf(v1, w1.w, a.w));
            }
        }
        lds_part[px*16 + sub] = a;
    }
    __syncthreads();
    if (tid < 32) {
        float sx = b_off[0], sy = b_off[1], sz = b_off[2], sw = b_off[3];
        #pragma unroll
        for (int k = 0; k < 16; ++k) {
            float4 p = lds_part[tid*16 + k];
            sx += p.x; sy += p.y; sz += p.z; sw += p.w;
        }
        lds_po[tid] = make_float4(sx, sy, fmaxf(sz, 0.f) + 1.f, fmaxf(sw, 0.f) + 1.f);
    }
    __syncthreads();

    // ---- Phase A: thread = px(32) x tap-half(2) x oct(8) ----
    {
        int oct = tid & 7, tp = (tid >> 3) & 1, pxl = tid >> 4;
        float4 o4 = lds_po[pxl];
        float off0 = o4.x, off1 = o4.y, s1 = o4.z, s2 = o4.w;
        int j  = j0 + pxl;
        int nt = pxl >> 4, pc = pxl & 15;
        int q  = oct & 3;
        int slot = (pc ^ (q << 1)) + (q << 4);

        for (int t = tp ? 5 : 0; t < (tp ? 9 : 5); ++t) {
            float ys = (float)(i - 1) + (float)(t/3 - 1)*s1 + off0;
            float xs = (float)(j - 1) + (float)(t%3 - 1)*s2 + off1;
            float y0f = floorf(ys), x0f = floorf(xs);
            float wy = ys - y0f, wx = xs - x0f;
            float vy0 = (y0f >=  0.f && y0f <= 127.f) ? 1.f : 0.f;
            float vy1 = (y0f >= -1.f && y0f <= 126.f) ? 1.f : 0.f;
            float vx0 = (x0f >=  0.f && x0f <= 127.f) ? 1.f : 0.f;
            float vx1 = (x0f >= -1.f && x0f <= 126.f) ? 1.f : 0.f;
            float w00 = (1.f-wy)*(1.f-wx)*vy0*vx0, w01 = (1.f-wy)*wx*vy0*vx1;
            float w10 = wy*(1.f-wx)*vy1*vx0,       w11 = wy*wx*vy1*vx1;
            int iy0 = min(max((int)y0f,     0), 127), iy1 = min(max((int)y0f + 1, 0), 127);
            int ix0 = min(max((int)x0f,     0), 127), ix1 = min(max((int)x0f + 1, 0), 127);
            const unsigned short* p00 = xb + (size_t)(iy0*Wd + ix0)*Cd + oct*8;
            const unsigned short* p01 = xb + (size_t)(iy0*Wd + ix1)*Cd + oct*8;
            const unsigned short* p10 = xb + (size_t)(iy1*Wd + ix0)*Cd + oct*8;
            const unsigned short* p11 = xb + (size_t)(iy1*Wd + ix1)*Cd + oct*8;
            uint4 u00 = *(const uint4*)p00, u01 = *(const uint4*)p01;
            uint4 u10 = *(const uint4*)p10, u11 = *(const uint4*)p11;
            unsigned a00[4] = {u00.x,u00.y,u00.z,u00.w}, a01[4] = {u01.x,u01.y,u01.z,u01.w};
            unsigned a10[4] = {u10.x,u10.y,u10.z,u10.w}, a11[4] = {u11.x,u11.y,u11.z,u11.w};
            unsigned pk[4];
            #pragma unroll
            for (int e = 0; e < 4; ++e) {
                float vlo = w00*bflo(a00[e]) + w01*bflo(a01[e]) + w10*bflo(a10[e]) + w11*bflo(a11[e]);
                float vhi = w00*bfhi(a00[e]) + w01*bfhi(a01[e]) + w10*bfhi(a10[e]) + w11*bfhi(a11[e]);
                pk[e] = (unsigned)f2bf(vlo) | ((unsigned)f2bf(vhi) << 16);
            }
            int ks = 2*t + (oct >> 2);
            lds_b[(ks*2 + nt)*64 + slot] = make_uint4(pk[0], pk[1], pk[2], pk[3]);
        }
    }
    __syncthreads();

    // ---- Phase B: 8 waves; wave = co-group(4) x px-half(2); 16co x 16px tile ----
    {
        int w = tid >> 6, l = tid & 63;
        int cg = w & 3, half = w >> 2;
        int pcB = l & 15, qB = l >> 4;
        int physl = (pcB ^ (qB << 1)) + (qB << 4);
        f32x4 acc = {0.f, 0.f, 0.f, 0.f};
        const short* wrow = g_wbf + (size_t)(cg*16 + pcB)*576;
        for (int ks = 0; ks < KS; ++ks) {
            short8 a  = *(const short8*)(wrow + ks*32 + qB*8);
            short8 bb = *(const short8*)&lds_b[(ks*2 + half)*64 + physl];
            acc = __builtin_amdgcn_mfma_f32_16x16x32_bf16(a, bb, acc, 0, 0, 0);
        }
        #pragma unroll
        for (int rr = 0; rr < 4; ++rr) {
            int co = cg*16 + qB*4 + rr;
            out[((size_t)(b*COd + co)*Hd + i)*Wd + j0 + half*16 + pcB] = acc[rr] + bias[co];
        }
    }
}

extern "C" void kernel_launch(void* const* d_in, const int* in_sizes, int n_in,
                              void* d_out, int out_size, void* d_ws, size_t ws_size,
                              hipStream_t stream) {
    const float* x      = (const float*)d_in[0];
    const float* w_off  = (const float*)d_in[1];
    const float* b_off  = (const float*)d_in[2];
    const float* weight = (const float*)d_in[3];
    const float* bias   = (const float*)d_in[4];
    float* out = (float*)d_out;

    hipLaunchKernelGGL(k_prep,   dim3(665),  dim3(256), 0, stream, x, weight, w_off);
    hipLaunchKernelGGL(k_deform, dim3(2048), dim3(512), 0, stream, b_off, bias, out);
}

// Round 5
// 108.012 us; speedup vs baseline: 1.1882x; 1.1882x over previous
//
#include <hip/hip_runtime.h>

#define Hd 128
#define Wd 128
#define Cd 64
#define COd 64
#define Bd 4
#define HWd (Hd*Wd)
#define KS 18   // 576 / 32 K-steps

typedef __attribute__((ext_vector_type(8))) short  short8;
typedef __attribute__((ext_vector_type(4))) float  f32x4;

// Static device scratch.
__device__ __align__(16) short g_wbf[COd*576];                   // bf16 W[co][k], k=t*64+c
__device__ __align__(16) float g_wtoff[9*Cd*4];                  // w_off^T [t][c][o]
__device__ __align__(16) unsigned short g_xt[(size_t)Bd*HWd*Cd]; // bf16 NHWC x

static __device__ __forceinline__ unsigned short f2bf(float v) {
    unsigned u = __float_as_uint(v);
    u += 0x7FFFu + ((u >> 16) & 1u);   // RNE
    return (unsigned short)(u >> 16);
}
static __device__ __forceinline__ float bflo(unsigned u) { return __uint_as_float(u << 16); }
static __device__ __forceinline__ float bfhi(unsigned u) { return __uint_as_float(u & 0xFFFF0000u); }

// One prep kernel: [0,512) NHWC repack ; [512,656) W->bf16 ; [656,665) w_off transpose.
__global__ __launch_bounds__(256) void k_prep(const float* __restrict__ x,
                                              const float* __restrict__ weight,
                                              const float* __restrict__ w_off) {
    int bid = blockIdx.x;
    if (bid < 512) {
        int b = bid >> 7, y = bid & 127;
        int px = threadIdx.x & 127;
        int h  = threadIdx.x >> 7;
        const float* xb = x + (size_t)b*Cd*HWd + y*Wd + px;
        unsigned short* ob = g_xt + ((size_t)(b*HWd) + y*Wd + px)*Cd + h*32;
        #pragma unroll
        for (int oct = 0; oct < 4; ++oct) {
            unsigned pk[4];
            #pragma unroll
            for (int e = 0; e < 4; ++e) {
                float v0 = xb[(size_t)(h*32 + oct*8 + 2*e    )*HWd];
                float v1 = xb[(size_t)(h*32 + oct*8 + 2*e + 1)*HWd];
                pk[e] = (unsigned)f2bf(v0) | ((unsigned)f2bf(v1) << 16);
            }
            *(uint4*)(ob + oct*8) = make_uint4(pk[0], pk[1], pk[2], pk[3]);
        }
    } else if (bid < 656) {
        int g = (bid - 512)*256 + threadIdx.x;     // 64*576
        if (g < COd*576) {
            int co = g / 576, k = g % 576;
            int t = k >> 6, c = k & 63;            // k = t*64 + c
            g_wbf[g] = (short)f2bf(weight[(co*Cd + c)*9 + t]);
        }
    } else {
        int g = (bid - 656)*256 + threadIdx.x;     // 9*64*4 = 2304
        if (g < 9*Cd*4) {
            int t = g >> 8, c = (g >> 2) & 63, o = g & 3;
            g_wtoff[g] = w_off[(o*Cd + c)*9 + t];
        }
    }
}

__global__ __launch_bounds__(256, 4) void k_deform(const float* __restrict__ b_off,
                                                   const float* __restrict__ bias,
                                                   float* __restrict__ out) {
    __shared__ uint4 lds_b[KS*2*64];    // 36864 B
    int gid = blockIdx.x;               // 2048 = b*512 + i*4 + jq
    int b  = gid >> 9;
    int r  = gid & 511;
    int i  = r >> 2;
    int j0 = (r & 3) << 5;
    int w  = threadIdx.x >> 6;
    int l  = threadIdx.x & 63;

    // Lane map shared by fused conv + Phase A: 8 px x 8 channel-octets per wave.
    int oct = l & 7, px8 = l >> 3;
    int pxl = w*8 + px8;                // 0..31
    int j   = j0 + pxl;
    const unsigned short* xb = g_xt + (size_t)b*HWd*Cd;

    // ---- Fused offsets conv (in-register, no LDS/barrier) ----
    float4 a = make_float4(0.f, 0.f, 0.f, 0.f);
    #pragma unroll 3
    for (int t = 0; t < 9; ++t) {
        int yy = i + t/3 - 1, xx = j + t%3 - 1;
        if (yy >= 0 && yy <= 127 && xx >= 0 && xx <= 127) {
            uint4 u = *(const uint4*)(xb + (size_t)(yy*Wd + xx)*Cd + oct*8);
            unsigned aa[4] = {u.x, u.y, u.z, u.w};
            #pragma unroll
            for (int e = 0; e < 4; ++e) {
                int c = oct*8 + 2*e;
                float v0 = bflo(aa[e]), v1 = bfhi(aa[e]);
                float4 w0 = *(const float4*)(g_wtoff + (t*Cd + c    )*4);
                float4 w1 = *(const float4*)(g_wtoff + (t*Cd + c + 1)*4);
                a.x = fmaf(v0, w0.x, fmaf(v1, w1.x, a.x));
                a.y = fmaf(v0, w0.y, fmaf(v1, w1.y, a.y));
                a.z = fmaf(v0, w0.z, fmaf(v1, w1.z, a.z));
                a.w = fmaf(v0, w0.w, fmaf(v1, w1.w, a.w));
            }
        }
    }
    #pragma unroll
    for (int m = 1; m < 8; m <<= 1) {   // butterfly over oct lanes -> all 8 hold the sum
        a.x += __shfl_xor(a.x, m, 64);
        a.y += __shfl_xor(a.y, m, 64);
        a.z += __shfl_xor(a.z, m, 64);
        a.w += __shfl_xor(a.w, m, 64);
    }
    float off0 = a.x + b_off[0];
    float off1 = a.y + b_off[1];
    float s1   = fmaxf(a.z + b_off[2], 0.f) + 1.f;
    float s2   = fmaxf(a.w + b_off[3], 0.f) + 1.f;

    // ---- Phase A: bilinear sample 32px x 576k into LDS (B-fragment order) ----
    {
        int nt = pxl >> 4, pc = pxl & 15;
        int q  = oct & 3;
        int slot = (pc ^ (q << 1)) + (q << 4);   // bank swizzle

        #pragma unroll 3
        for (int t = 0; t < 9; ++t) {
            float ys = (float)(i - 1) + (float)(t/3 - 1)*s1 + off0;
            float xs = (float)(j - 1) + (float)(t%3 - 1)*s2 + off1;
            float y0f = floorf(ys), x0f = floorf(xs);
            float wy = ys - y0f, wx = xs - x0f;
            float vy0 = (y0f >=  0.f && y0f <= 127.f) ? 1.f : 0.f;
            float vy1 = (y0f >= -1.f && y0f <= 126.f) ? 1.f : 0.f;
            float vx0 = (x0f >=  0.f && x0f <= 127.f) ? 1.f : 0.f;
            float vx1 = (x0f >= -1.f && x0f <= 126.f) ? 1.f : 0.f;
            float w00 = (1.f-wy)*(1.f-wx)*vy0*vx0, w01 = (1.f-wy)*wx*vy0*vx1;
            float w10 = wy*(1.f-wx)*vy1*vx0,       w11 = wy*wx*vy1*vx1;
            int iy0 = min(max((int)y0f,     0), 127), iy1 = min(max((int)y0f + 1, 0), 127);
            int ix0 = min(max((int)x0f,     0), 127), ix1 = min(max((int)x0f + 1, 0), 127);
            const unsigned short* p00 = xb + (size_t)(iy0*Wd + ix0)*Cd + oct*8;
            const unsigned short* p01 = xb + (size_t)(iy0*Wd + ix1)*Cd + oct*8;
            const unsigned short* p10 = xb + (size_t)(iy1*Wd + ix0)*Cd + oct*8;
            const unsigned short* p11 = xb + (size_t)(iy1*Wd + ix1)*Cd + oct*8;
            uint4 u00 = *(const uint4*)p00, u01 = *(const uint4*)p01;
            uint4 u10 = *(const uint4*)p10, u11 = *(const uint4*)p11;
            unsigned a00[4] = {u00.x,u00.y,u00.z,u00.w}, a01[4] = {u01.x,u01.y,u01.z,u01.w};
            unsigned a10[4] = {u10.x,u10.y,u10.z,u10.w}, a11[4] = {u11.x,u11.y,u11.z,u11.w};
            unsigned pk[4];
            #pragma unroll
            for (int e = 0; e < 4; ++e) {
                float vlo = w00*bflo(a00[e]) + w01*bflo(a01[e]) + w10*bflo(a10[e]) + w11*bflo(a11[e]);
                float vhi = w00*bfhi(a00[e]) + w01*bfhi(a01[e]) + w10*bfhi(a10[e]) + w11*bfhi(a11[e]);
                pk[e] = (unsigned)f2bf(vlo) | ((unsigned)f2bf(vhi) << 16);
            }
            int ks = 2*t + (oct >> 2);
            lds_b[(ks*2 + nt)*64 + slot] = make_uint4(pk[0], pk[1], pk[2], pk[3]);
        }
    }
    __syncthreads();

    // ---- Phase B: 16co x 32px GEMM tile per wave ----
    {
        f32x4 acc0 = {0.f,0.f,0.f,0.f};
        f32x4 acc1 = {0.f,0.f,0.f,0.f};
        int pcB = l & 15, qB = l >> 4;
        int physl = (pcB ^ (qB << 1)) + (qB << 4);
        const short* wrow = g_wbf + (size_t)(w*16 + pcB)*576;
        for (int ks = 0; ks < KS; ++ks) {
            short8 av = *(const short8*)(wrow + ks*32 + qB*8);
            short8 b0 = *(const short8*)&lds_b[(ks*2 + 0)*64 + physl];
            short8 b1 = *(const short8*)&lds_b[(ks*2 + 1)*64 + physl];
            acc0 = __builtin_amdgcn_mfma_f32_16x16x32_bf16(av, b0, acc0, 0, 0, 0);
            acc1 = __builtin_amdgcn_mfma_f32_16x16x32_bf16(av, b1, acc1, 0, 0, 0);
        }
        #pragma unroll
        for (int rr = 0; rr < 4; ++rr) {
            int co = w*16 + qB*4 + rr;
            float bco = bias[co];
            size_t base = ((size_t)(b*COd + co)*Hd + i)*Wd + j0;
            out[base + pcB]      = acc0[rr] + bco;
            out[base + 16 + pcB] = acc1[rr] + bco;
        }
    }
}

extern "C" void kernel_launch(void* const* d_in, const int* in_sizes, int n_in,
                              void* d_out, int out_size, void* d_ws, size_t ws_size,
                              hipStream_t stream) {
    const float* x      = (const float*)d_in[0];
    const float* w_off  = (const float*)d_in[1];
    const float* b_off  = (const float*)d_in[2];
    const float* weight = (const float*)d_in[3];
    const float* bias   = (const float*)d_in[4];
    float* out = (float*)d_out;

    hipLaunchKernelGGL(k_prep,   dim3(665),  dim3(256), 0, stream, x, weight, w_off);
    hipLaunchKernelGGL(k_deform, dim3(2048), dim3(256), 0, stream, b_off, bias, out);
}